// Round 2
// baseline (355.240 us; speedup 1.0000x reference)
//
#include <hip/hip_runtime.h>

// ConvCapsLayer: A=32,B=32,K=3,P=4,STRIDE=2,ITERS=3  — all fp32
// x: (2,32,32,512) f32   weights: (288,32,4,4) f32   out: (2,15,15,512) f32
// One block per (patch n, out-capsule j): N=2*15*15=450, j in [0,32) -> 14400 blocks.
// Thread t (<288) owns input-capsule i=t: computes v[i,:] = X_i(4x4) * W_ij(4x4),
// then 3 dynamic-routing iterations with wave-shuffle + 5-wave LDS reductions.

#define OH 15
#define OW 15
#define NB 2
#define KKA 288
#define NITERS 3
#define EPS_ 1e-8f

__global__ __launch_bounds__(320) void convcaps_kernel(
    const float* __restrict__ x,   // (2,32,32,512)
    const float* __restrict__ w,   // (288,32,16)
    float* __restrict__ out)       // (450,512)
{
    const int blk  = blockIdx.x;      // 0..14399
    const int n    = blk >> 5;        // patch 0..449
    const int j    = blk & 31;        // out capsule
    const int t    = threadIdx.x;     // 0..319
    const int lane = t & 63;
    const int wv   = t >> 6;          // 0..4
    const bool active = (t < KKA);

    // n -> (batch, oy, ox)
    const int batch = n / (OH * OW);
    const int rem   = n - batch * OH * OW;
    const int oy    = rem / OW;
    const int ox    = rem - oy * OW;

    float v[16];
#pragma unroll
    for (int q = 0; q < 16; ++q) v[q] = 0.0f;
    float logit = 0.0f;

    if (active) {
        // i = t -> (kh, kw, a);  i = kh*96 + kw*32 + a
        const int a  = t & 31;
        const int kw = (t >> 5) % 3;
        const int kh = t / 96;
        const int h  = oy * 2 + kh;
        const int wc = ox * 2 + kw;

        // x[n,i,p,r] = x[batch, h, wc, a*16 + p*4 + r] : 16 contiguous f32 (64B)
        const float4* xv = reinterpret_cast<const float4*>(
            x + (((size_t)(batch * 32 + h) * 32 + wc) * 512 + a * 16));
        float4 x0 = xv[0], x1 = xv[1], x2 = xv[2], x3 = xv[3];
        float xr[16] = { x0.x,x0.y,x0.z,x0.w, x1.x,x1.y,x1.z,x1.w,
                         x2.x,x2.y,x2.z,x2.w, x3.x,x3.y,x3.z,x3.w };

        // W[i,j,r,q] : 16 contiguous f32 at ((i*32 + j)*16)
        const float4* wvv = reinterpret_cast<const float4*>(
            w + ((size_t)t * 32 + j) * 16);
        float4 w0 = wvv[0], w1 = wvv[1], w2 = wvv[2], w3 = wvv[3];
        float wr[16] = { w0.x,w0.y,w0.z,w0.w, w1.x,w1.y,w1.z,w1.w,
                         w2.x,w2.y,w2.z,w2.w, w3.x,w3.y,w3.z,w3.w };

        // v[p,q] = sum_r xr[p,r] * wr[r,q]
#pragma unroll
        for (int p = 0; p < 4; ++p) {
#pragma unroll
            for (int q = 0; q < 4; ++q) {
                v[p * 4 + q] = fmaf(xr[p*4+0], wr[0*4+q],
                               fmaf(xr[p*4+1], wr[1*4+q],
                               fmaf(xr[p*4+2], wr[2*4+q],
                                    xr[p*4+3] * wr[3*4+q])));
            }
        }
    }

    __shared__ float red[5][16];
    __shared__ float reds[5];

    float pvec[16];

    for (int it = 0; it < NITERS; ++it) {
        float r;
        if (it == 0) {
            r = 1.0f / 288.0f;          // softmax of zeros
        } else {
            // softmax over i (288 active threads)
            float ml = active ? logit : -1e30f;
#pragma unroll
            for (int off = 32; off > 0; off >>= 1)
                ml = fmaxf(ml, __shfl_xor(ml, off));
            if (lane == 0) reds[wv] = ml;
            __syncthreads();
            float m = fmaxf(fmaxf(fmaxf(reds[0], reds[1]), fmaxf(reds[2], reds[3])), reds[4]);
            float e = active ? __expf(logit - m) : 0.0f;
            float se = e;
#pragma unroll
            for (int off = 32; off > 0; off >>= 1)
                se += __shfl_xor(se, off);
            __syncthreads();             // finish reading reds (m) before rewrite
            if (lane == 0) reds[wv] = se;
            __syncthreads();
            float S = reds[0] + reds[1] + reds[2] + reds[3] + reds[4];
            r = e / S;
        }

        // s[q] = sum_i r_i * v[i,q]
        float c[16];
#pragma unroll
        for (int q = 0; q < 16; ++q) c[q] = active ? r * v[q] : 0.0f;
#pragma unroll
        for (int q = 0; q < 16; ++q) {
#pragma unroll
            for (int off = 32; off > 0; off >>= 1)
                c[q] += __shfl_xor(c[q], off);
        }
        __syncthreads();                 // previous red[]/reds reads done
        if (lane < 16) red[wv][lane] = c[lane];
        __syncthreads();

        // squash (computed redundantly by all threads from LDS broadcasts)
        float n2 = 0.0f;
#pragma unroll
        for (int q = 0; q < 16; ++q) {
            float sq = red[0][q] + red[1][q] + red[2][q] + red[3][q] + red[4][q];
            pvec[q] = sq;
            n2 += sq * sq;
        }
        float scale = n2 / ((1.0f + n2) * sqrtf(n2 + EPS_));
#pragma unroll
        for (int q = 0; q < 16; ++q) pvec[q] *= scale;

        if (it < NITERS - 1 && active) {
            float d = 0.0f;
#pragma unroll
            for (int q = 0; q < 16; ++q) d = fmaf(v[q], pvec[q], d);
            logit += d;
        }
    }

    if (t < 16) {
        out[(size_t)n * 512 + j * 16 + t] = pvec[t];
    }
}

extern "C" void kernel_launch(void* const* d_in, const int* in_sizes, int n_in,
                              void* d_out, int out_size, void* d_ws, size_t ws_size,
                              hipStream_t stream) {
    const float* x = (const float*)d_in[0];
    const float* w = (const float*)d_in[1];
    float* out = (float*)d_out;
    const int nblocks = NB * OH * OW * 32;   // 450 * 32 = 14400
    convcaps_kernel<<<nblocks, 320, 0, stream>>>(x, w, out);
}

// Round 3
// 112.958 us; speedup vs baseline: 3.1449x; 3.1449x over previous
//
#include <hip/hip_runtime.h>

// ConvCapsLayer: A=32,B=32,K=3,P=4,STRIDE=2,ITERS=3 — all fp32
// x: (2,32,32,512) f32   weights: (288,32,16) f32   out: (450,512) f32
// One WAVE per (patch n, out-capsule j). Lane owns i = lane + 64k, k=0..4
// (k=4 only for lane<32). v[5][16] in registers. Routing reductions via
// DPP/swizzle split-butterfly; p broadcast via 256B LDS.
// Block = 256 threads = 4 waves = 4 consecutive j's (shared n -> x L1 reuse).

#define OH 15
#define OW 15
#define NITERS 3
#define EPS_ 1e-8f

__global__ __launch_bounds__(256, 3) void convcaps_kernel(
    const float* __restrict__ x,   // (2,32,32,512)
    const float* __restrict__ w,   // (288,32,16)
    float* __restrict__ out)       // (450,512)
{
    const int blk  = blockIdx.x;      // 0..3599
    const int n    = blk >> 3;        // patch 0..449
    const int jg   = blk & 7;
    const int t    = threadIdx.x;
    const int wv   = t >> 6;          // 0..3
    const int lane = t & 63;
    const int j    = jg * 4 + wv;     // out capsule 0..31

    const int batch = n / (OH * OW);
    const int rem   = n - batch * OH * OW;
    const int oy    = rem / OW;
    const int ox    = rem - oy * OW;

    const bool has5 = (lane < 32);

    float v[5][16];
    float logit[5] = {0.f, 0.f, 0.f, 0.f, 0.f};

    // ---- compute v[k][p*4+q] = sum_r X[i,p,r] * W[i,j,r,q], i = lane+64k ----
#pragma unroll
    for (int k = 0; k < 5; ++k) {
        if (k == 4 && !has5) {
#pragma unroll
            for (int q = 0; q < 16; ++q) v[4][q] = 0.f;
        } else {
            const int i  = lane + 64 * k;
            const int a  = i & 31;
            const int kw = (i >> 5) % 3;
            const int kh = i / 96;
            const int h  = oy * 2 + kh;
            const int wc = ox * 2 + kw;

            const float4* xv = reinterpret_cast<const float4*>(
                x + (((size_t)(batch * 32 + h) * 32 + wc) * 512 + a * 16));
            float4 x0 = xv[0], x1 = xv[1], x2 = xv[2], x3 = xv[3];
            float xr[16] = { x0.x,x0.y,x0.z,x0.w, x1.x,x1.y,x1.z,x1.w,
                             x2.x,x2.y,x2.z,x2.w, x3.x,x3.y,x3.z,x3.w };

            const float4* wp = reinterpret_cast<const float4*>(
                w + ((size_t)i * 32 + j) * 16);
            float4 w0 = wp[0], w1 = wp[1], w2 = wp[2], w3 = wp[3];
            float wr[16] = { w0.x,w0.y,w0.z,w0.w, w1.x,w1.y,w1.z,w1.w,
                             w2.x,w2.y,w2.z,w2.w, w3.x,w3.y,w3.z,w3.w };

#pragma unroll
            for (int p = 0; p < 4; ++p)
#pragma unroll
                for (int q = 0; q < 4; ++q)
                    v[k][p*4+q] = fmaf(xr[p*4+0], wr[0*4+q],
                                  fmaf(xr[p*4+1], wr[1*4+q],
                                  fmaf(xr[p*4+2], wr[2*4+q],
                                       xr[p*4+3] * wr[3*4+q])));
        }
    }

    __shared__ float pbuf[4][16];

#pragma unroll
    for (int it = 0; it < NITERS; ++it) {
        // ---- routing weights r[k] ----
        float r[5];
        if (it == 0) {
            const float u = 1.0f / 288.0f;
            r[0]=u; r[1]=u; r[2]=u; r[3]=u; r[4] = has5 ? u : 0.f;
        } else {
            float ml = fmaxf(fmaxf(logit[0], logit[1]), fmaxf(logit[2], logit[3]));
            ml = fmaxf(ml, has5 ? logit[4] : -1e30f);
#pragma unroll
            for (int off = 1; off < 64; off <<= 1)
                ml = fmaxf(ml, __shfl_xor(ml, off));
            float e0 = __expf(logit[0]-ml), e1 = __expf(logit[1]-ml);
            float e2 = __expf(logit[2]-ml), e3 = __expf(logit[3]-ml);
            float e4 = has5 ? __expf(logit[4]-ml) : 0.f;
            float se = e0+e1+e2+e3+e4;
#pragma unroll
            for (int off = 1; off < 64; off <<= 1)
                se += __shfl_xor(se, off);
            float rinv = 1.0f / se;
            r[0]=e0*rinv; r[1]=e1*rinv; r[2]=e2*rinv; r[3]=e3*rinv; r[4]=e4*rinv;
        }

        // ---- local weighted sum: c[q] = sum_k r[k]*v[k][q] ----
        float c[16];
#pragma unroll
        for (int q = 0; q < 16; ++q)
            c[q] = fmaf(r[0], v[0][q], fmaf(r[1], v[1][q],
                   fmaf(r[2], v[2][q], fmaf(r[3], v[3][q], r[4]*v[4][q]))));

        // ---- cross-lane sum of 16 comps over 64 lanes (split butterfly) ----
        // full steps (DPP quad_perm, cheap):
#pragma unroll
        for (int q = 0; q < 16; ++q) c[q] += __shfl_xor(c[q], 1);
#pragma unroll
        for (int q = 0; q < 16; ++q) c[q] += __shfl_xor(c[q], 2);
        // split steps: after these, lane holds comp q=(lane>>2)&15 (dup x4 in quad)
        float s8[8];
        {
            const bool b = (lane >> 2) & 1;
#pragma unroll
            for (int m = 0; m < 8; ++m) {
                float send = b ? c[2*m]   : c[2*m+1];
                float keep = b ? c[2*m+1] : c[2*m];
                s8[m] = keep + __shfl_xor(send, 4);
            }
        }
        float s4[4];
        {
            const bool b = (lane >> 3) & 1;
#pragma unroll
            for (int m = 0; m < 4; ++m) {
                float send = b ? s8[2*m]   : s8[2*m+1];
                float keep = b ? s8[2*m+1] : s8[2*m];
                s4[m] = keep + __shfl_xor(send, 8);
            }
        }
        float s2[2];
        {
            const bool b = (lane >> 4) & 1;
#pragma unroll
            for (int m = 0; m < 2; ++m) {
                float send = b ? s4[2*m]   : s4[2*m+1];
                float keep = b ? s4[2*m+1] : s4[2*m];
                s2[m] = keep + __shfl_xor(send, 16);
            }
        }
        float s1;
        {
            const bool b = (lane >> 5) & 1;
            float send = b ? s2[0] : s2[1];
            float keep = b ? s2[1] : s2[0];
            s1 = keep + __shfl_xor(send, 32);
        }

        // ---- squash: n2 = sum over the 16 quad-held comps ----
        float t2 = s1 * s1;
        t2 += __shfl_xor(t2, 4);
        t2 += __shfl_xor(t2, 8);
        t2 += __shfl_xor(t2, 16);
        t2 += __shfl_xor(t2, 32);
        const float n2 = t2;
        const float scale = n2 / ((1.0f + n2) * sqrtf(n2 + EPS_));
        const float pval = s1 * scale;   // comp (lane>>2)&15 of p

        if (it < NITERS - 1) {
            // broadcast p[16] to all lanes via LDS
            __syncthreads();
            if ((lane & 3) == 0) pbuf[wv][lane >> 2] = pval;
            __syncthreads();
            const float4* pb = reinterpret_cast<const float4*>(pbuf[wv]);
            float4 p0 = pb[0], p1 = pb[1], p2 = pb[2], p3 = pb[3];
            float p[16] = { p0.x,p0.y,p0.z,p0.w, p1.x,p1.y,p1.z,p1.w,
                            p2.x,p2.y,p2.z,p2.w, p3.x,p3.y,p3.z,p3.w };
            // logits update: logit[k] += v[k][:] . p    (v[4]=0 for !has5)
#pragma unroll
            for (int k = 0; k < 5; ++k) {
                float d = 0.f;
#pragma unroll
                for (int q = 0; q < 16; ++q) d = fmaf(v[k][q], p[q], d);
                logit[k] += d;
            }
        } else {
            if ((lane & 3) == 0)
                out[(size_t)n * 512 + j * 16 + (lane >> 2)] = pval;
        }
    }
}

extern "C" void kernel_launch(void* const* d_in, const int* in_sizes, int n_in,
                              void* d_out, int out_size, void* d_ws, size_t ws_size,
                              hipStream_t stream) {
    const float* x = (const float*)d_in[0];
    const float* w = (const float*)d_in[1];
    float* out = (float*)d_out;
    const int nblocks = 450 * 8;   // (n) x (j-groups of 4 waves)
    convcaps_kernel<<<nblocks, 256, 0, stream>>>(x, w, out);
}